// Round 5
// baseline (872.077 us; speedup 1.0000x reference)
//
#include <hip/hip_runtime.h>
#include <math.h>

#define HW 4096   // 64*64

typedef __attribute__((ext_vector_type(8))) short short8;
typedef __attribute__((ext_vector_type(4))) float floatx4;

__device__ inline unsigned short f2bf(float f) {
    unsigned int u = __float_as_uint(f);
    unsigned int r = (u + 0x7fffu + ((u >> 16) & 1u)) >> 16;
    return (unsigned short)r;
}
__device__ inline float bf2f(unsigned short u) {
    return __uint_as_float(((unsigned int)u) << 16);
}

// ---------------- zero scratch (uint4 stores)
__global__ void zero_kernel(uint4* __restrict__ p, int n)
{
    int i = blockIdx.x * 256 + threadIdx.x;
    if (i < n) p[i] = make_uint4(0u, 0u, 0u, 0u);
}

// ---------------- weight prepack: W[CO][CI][K][K] fp32 -> Wp[kh][kw][co][ci] bf16
__global__ void prepack_w(const float* __restrict__ w, unsigned short* __restrict__ wp,
                          int CO, int CI, int KK)
{
    int i = blockIdx.x * 256 + threadIdx.x;
    if (i >= CO * CI * KK) return;
    int ci = i % CI;
    int t = i / CI;
    int co = t % CO;
    int kk = t / CO;
    wp[i] = f2bf(w[(co * CI + ci) * KK + kk]);
}

// ---------------- 1x1 conv: 4 pixels/thread (float4), 8 co/thread, weights in LDS
__global__ void __launch_bounds__(256)
conv1x1_v4(const float* __restrict__ in, const float* __restrict__ w,
           const float* __restrict__ bias, float* __restrict__ out,
           int CI, int CO, int do_affine,
           const float* __restrict__ s, const float* __restrict__ o,
           const float* __restrict__ addbuf, unsigned short* __restrict__ xt)
{
    __shared__ float wl[256 * 8];
    int tid = threadIdx.x;
    int c0 = blockIdx.y * 8;
    int b = blockIdx.z;
    for (int i = tid; i < CI * 8; i += 256) {
        int k = i & 7, ci = i >> 3;
        wl[i] = w[(c0 + k) * CI + ci];
    }
    __syncthreads();
    int m = blockIdx.x * 1024 + tid * 4;
    floatx4 acc[8];
#pragma unroll
    for (int k = 0; k < 8; ++k) {
        float bv = bias[c0 + k];
        acc[k] = (floatx4){bv, bv, bv, bv};
    }
    const float* inb = in + (size_t)b * CI * HW + m;
#pragma unroll 4
    for (int ci = 0; ci < CI; ++ci) {
        floatx4 v = *(const floatx4*)(inb + (size_t)ci * HW);
#pragma unroll
        for (int k = 0; k < 8; ++k) {
            float wv = wl[ci * 8 + k];
            acc[k] += wv * v;
        }
    }
#pragma unroll
    for (int k = 0; k < 8; ++k) {
        floatx4 v = acc[k];
        if (do_affine) {
            float sc = s[c0 + k], of = o[c0 + k];
#pragma unroll
            for (int r = 0; r < 4; ++r) v[r] = fmaxf(v[r], 0.f) * sc + of;
        }
        size_t oidx = ((size_t)(b * CO + c0 + k)) * HW + m;
        if (addbuf) {
            floatx4 a = *(const floatx4*)(addbuf + oidx);
            v += a;
        }
        *(floatx4*)(out + oidx) = v;
        acc[k] = v;
    }
    if (xt) {
#pragma unroll
        for (int r = 0; r < 4; ++r) {
            int mm = m + r;
            union { unsigned short u16[8]; uint4 q; } pk;
#pragma unroll
            for (int k = 0; k < 8; ++k) pk.u16[k] = f2bf(acc[k][r]);
            int h = mm >> 6, wc = mm & 63;
            *(uint4*)(xt + ((size_t)b * 4624 + (h + 2) * 68 + (wc + 2)) * 128 + c0) = pk.q;
        }
    }
}

// ---------------- KxK conv as implicit-GEMM bf16 MFMA (unchanged from R4)
template<int K, int CO, int NB>
__global__ void __launch_bounds__(256)
convk_mfma(const unsigned short* __restrict__ xt, const unsigned short* __restrict__ wp,
           const float* __restrict__ bias, float* __restrict__ out,
           int OB, int co_off, int do_affine,
           const float* __restrict__ s, const float* __restrict__ o,
           unsigned short* __restrict__ incT)
{
    constexpr int CI = 128;
    constexpr int PAD = K / 2;
    constexpr int RO = 2 - PAD;
    int tid = threadIdx.x;
    int wave = tid >> 6, lane = tid & 63;
    int h = blockIdx.x, b = blockIdx.y;
    int co0 = wave * 16 * NB;
    int n = lane & 15, q = lane >> 4;
    floatx4 acc[4][NB];
#pragma unroll
    for (int mt = 0; mt < 4; ++mt)
#pragma unroll
        for (int nt = 0; nt < NB; ++nt) acc[mt][nt] = (floatx4){0.f, 0.f, 0.f, 0.f};

    const unsigned short* xb = xt + (size_t)b * (68 * 68 * 128) + 8 * q;
    for (int ci0 = 0; ci0 < CI; ci0 += 32) {
#pragma unroll
        for (int kh = 0; kh < K; ++kh) {
            const unsigned short* xrow = xb + (size_t)(((h + kh + RO) * 68 + RO) * 128 + ci0);
            const unsigned short* wrow = wp + (size_t)(kh * K * CO * CI) + ci0 + 8 * q;
#pragma unroll
            for (int kw = 0; kw < K; ++kw) {
                short8 bfr[NB];
#pragma unroll
                for (int nt = 0; nt < NB; ++nt)
                    bfr[nt] = *(const short8*)(wrow + (size_t)((kw * CO + co0 + nt * 16 + n) * CI));
#pragma unroll
                for (int mt = 0; mt < 4; ++mt) {
                    short8 afr = *(const short8*)(xrow + (mt * 16 + n + kw) * 128);
#pragma unroll
                    for (int nt = 0; nt < NB; ++nt)
                        acc[mt][nt] = __builtin_amdgcn_mfma_f32_16x16x32_bf16(afr, bfr[nt], acc[mt][nt], 0, 0, 0);
                }
            }
        }
    }
    int px0 = h * 64 + q * 4;
#pragma unroll
    for (int nt = 0; nt < NB; ++nt) {
        int co = co0 + nt * 16 + n;
        float bi = bias[co];
        float sc = do_affine ? s[co] : 1.f;
        float of = do_affine ? o[co] : 0.f;
        float* ob = out + ((size_t)(b * OB + co_off + co)) * HW;
        unsigned short* tb = incT ? incT + (size_t)b * (4096 * 128) + co : nullptr;
#pragma unroll
        for (int mt = 0; mt < 4; ++mt)
#pragma unroll
            for (int r = 0; r < 4; ++r) {
                int px = px0 + mt * 16 + r;
                float v = acc[mt][nt][r] + bi;
                if (do_affine) v = fmaxf(v, 0.f) * sc + of;
                ob[px] = v;
                if (incT) tb[(size_t)px * 128] = f2bf(v);
            }
    }
}

// ---------------- cosine similarity over groups of 128 consecutive floats
__global__ void sim_kernel(const float* __restrict__ r1, const float* __restrict__ r2,
                           float* __restrict__ sim)
{
    int gw = blockIdx.x * 4 + (threadIdx.x >> 6);
    int lane = threadIdx.x & 63;
    int b = gw >> 12, n = gw & 4095;
    const float* p1 = r1 + (size_t)b * 524288 + (size_t)n * 128;
    const float* p2 = r2 + (size_t)b * 524288 + (size_t)n * 128;
    float a0 = p1[lane], a1 = p1[lane + 64];
    float b0 = p2[lane], b1 = p2[lane + 64];
    float dot = a0 * b0 + a1 * b1;
    float n1 = a0 * a0 + a1 * a1;
    float n2 = b0 * b0 + b1 * b1;
    for (int m = 32; m; m >>= 1) {
        dot += __shfl_xor(dot, m);
        n1  += __shfl_xor(n1, m);
        n2  += __shfl_xor(n2, m);
    }
    if (lane == 0) sim[b * 4096 + n] = dot / fmaxf(sqrtf(n1) * sqrtf(n2), 1e-8f);
}

// ---------------- x = concat(dif1, dif2): LDS-transposed, fully coalesced
__global__ void __launch_bounds__(256)
x_kernel2(const float* __restrict__ r1, const float* __restrict__ r2,
          const float* __restrict__ sim, float* __restrict__ xo)
{
    __shared__ float ls1[32 * 129], ls2[32 * 129];
    int b = blockIdx.y, p0 = blockIdx.x * 32, tid = threadIdx.x;
    const float* F1 = r1 + (size_t)b * 524288;
    const float* F2 = r2 + (size_t)b * 524288;
    for (int i = tid; i < 32 * 128; i += 256) {
        int p = i >> 7, c = i & 127;
        ls1[p * 129 + c] = F1[p0 * 128 + i];
        ls2[p * 129 + c] = F2[p0 * 128 + i];
    }
    __syncthreads();
    for (int j = tid; j < 256 * 32; j += 256) {
        int p = j & 31, cc = j >> 5;
        int c = cc & 127;
        float sv = sim[b * 4096 + p0 + p];
        const float* F = (cc & 128) ? F2 : F1;
        float t1v = ((cc & 128) ? ls2 : ls1)[p * 129 + c];
        xo[(size_t)b * 1048576 + (size_t)cc * 4096 + p0 + p] = t1v * (1.f - sv) + F[(size_t)c * 4096 + p0 + p];
    }
}

// ---------------- attn = avgpool2(|sim1-sim2|) -> bf16, LDS-transposed
__global__ void __launch_bounds__(256)
simp_kernel2(const float* __restrict__ r1, const float* __restrict__ r2,
             const float* __restrict__ sim, unsigned short* __restrict__ attn_bf)
{
    __shared__ float lsd[64 * 129];
    int b = blockIdx.y, h2 = blockIdx.x, tid = threadIdx.x;
    const float* F1 = r1 + (size_t)b * 524288;
    const float* F2 = r2 + (size_t)b * 524288;
    const float* sb = sim + b * 4096;
    float acc[16] = {};
    int w2 = tid & 31;
    for (int dh = 0; dh < 2; ++dh) {
        int prow = h2 * 128 + dh * 64;
        __syncthreads();
        for (int i = tid; i < 64 * 128; i += 256) {
            int p = i >> 7, c = i & 127;
            lsd[p * 129 + c] = F1[(size_t)prow * 128 + i] - F2[(size_t)prow * 128 + i];
        }
        __syncthreads();
#pragma unroll
        for (int k = 0; k < 16; ++k) {
            int c = (tid >> 5) + 8 * k;
#pragma unroll
            for (int dw = 0; dw < 2; ++dw) {
                int pl = 2 * w2 + dw;
                int p = prow + pl;
                float d = lsd[pl * 129 + c] * sb[p]
                        + (F1[(size_t)c * 4096 + p] - F2[(size_t)c * 4096 + p]);
                acc[k] += fabsf(d);
            }
        }
    }
#pragma unroll
    for (int k = 0; k < 16; ++k) {
        int c = (tid >> 5) + 8 * k;
        attn_bf[(size_t)b * 131072 + (size_t)c * 1024 + h2 * 32 + w2] = f2bf(acc[k] * 0.25f);
    }
}

// ---------------- attention A1: per-row max partials (split-m)
__global__ void __launch_bounds__(256)
attnA_max(const unsigned short* __restrict__ attn_bf,
          const unsigned short* __restrict__ incT1, const unsigned short* __restrict__ incT2,
          float* __restrict__ pmax)
{
    __shared__ float lm[4][16];
    int pair = blockIdx.y;
    int b = pair & 3, br = pair >> 2;
    int z = blockIdx.z;
    int tid = threadIdx.x;
    int wave = tid >> 6, lane = tid & 63;
    int n0 = blockIdx.x * 16;
    int q = lane >> 4, col = lane & 15;
    const unsigned short* arow = attn_bf + ((size_t)(b * 1024 + n0 + col)) * 128 + q * 8;
    short8 afr[4];
#pragma unroll
    for (int kc = 0; kc < 4; ++kc) afr[kc] = *(const short8*)(arow + kc * 32);
    const unsigned short* ib = (br ? incT2 : incT1) + (size_t)b * 524288;
    float rm[4];
#pragma unroll
    for (int r = 0; r < 4; ++r) rm[r] = -3.0e38f;
    for (int mt = 0; mt < 16; ++mt) {
        int m = z * 1024 + wave * 256 + mt * 16 + col;
        const unsigned short* brow = ib + (size_t)m * 128 + q * 8;
        floatx4 acc = (floatx4){0.f, 0.f, 0.f, 0.f};
#pragma unroll
        for (int kc = 0; kc < 4; ++kc)
            acc = __builtin_amdgcn_mfma_f32_16x16x32_bf16(afr[kc], *(const short8*)(brow + kc * 32), acc, 0, 0, 0);
#pragma unroll
        for (int r = 0; r < 4; ++r) rm[r] = fmaxf(rm[r], acc[r]);
    }
#pragma unroll
    for (int d = 1; d < 16; d <<= 1)
#pragma unroll
        for (int r = 0; r < 4; ++r) rm[r] = fmaxf(rm[r], __shfl_xor(rm[r], d));
    if (col == 0) {
#pragma unroll
        for (int r = 0; r < 4; ++r) lm[wave][q * 4 + r] = rm[r];
    }
    __syncthreads();
    if (tid < 16) {
        float v = lm[0][tid];
        for (int w = 1; w < 4; ++w) v = fmaxf(v, lm[w][tid]);
        pmax[((size_t)pair * 4 + z) * 1024 + n0 + tid] = v;
    }
}

// ---------------- attention A2: merge max over z; zero sum
__global__ void attnA_merge(const float* __restrict__ pmax, float* __restrict__ mx,
                            float* __restrict__ sum)
{
    int i = blockIdx.x * 256 + threadIdx.x;   // 8192
    int pair = i >> 10, n = i & 1023;
    float v = pmax[((size_t)pair * 4 + 0) * 1024 + n];
    for (int z = 1; z < 4; ++z) v = fmaxf(v, pmax[((size_t)pair * 4 + z) * 1024 + n]);
    mx[i] = v;
    sum[i] = 0.f;
}

// ---------------- attention A3: sum of exp(S - mx) partials (split-m, atomicAdd)
__global__ void __launch_bounds__(256)
attnA_sum(const unsigned short* __restrict__ attn_bf,
          const unsigned short* __restrict__ incT1, const unsigned short* __restrict__ incT2,
          const float* __restrict__ mx, float* __restrict__ sum)
{
    __shared__ float ls[4][16];
    int pair = blockIdx.y;
    int b = pair & 3, br = pair >> 2;
    int z = blockIdx.z;
    int tid = threadIdx.x;
    int wave = tid >> 6, lane = tid & 63;
    int n0 = blockIdx.x * 16;
    int q = lane >> 4, col = lane & 15;
    const unsigned short* arow = attn_bf + ((size_t)(b * 1024 + n0 + col)) * 128 + q * 8;
    short8 afr[4];
#pragma unroll
    for (int kc = 0; kc < 4; ++kc) afr[kc] = *(const short8*)(arow + kc * 32);
    const unsigned short* ib = (br ? incT2 : incT1) + (size_t)b * 524288;
    floatx4 mxq = *(const floatx4*)(mx + pair * 1024 + n0 + q * 4);
    float rs[4] = {};
    for (int mt = 0; mt < 16; ++mt) {
        int m = z * 1024 + wave * 256 + mt * 16 + col;
        const unsigned short* brow = ib + (size_t)m * 128 + q * 8;
        floatx4 acc = (floatx4){0.f, 0.f, 0.f, 0.f};
#pragma unroll
        for (int kc = 0; kc < 4; ++kc)
            acc = __builtin_amdgcn_mfma_f32_16x16x32_bf16(afr[kc], *(const short8*)(brow + kc * 32), acc, 0, 0, 0);
#pragma unroll
        for (int r = 0; r < 4; ++r) rs[r] += __expf(acc[r] - mxq[r]);
    }
#pragma unroll
    for (int d = 1; d < 16; d <<= 1)
#pragma unroll
        for (int r = 0; r < 4; ++r) rs[r] += __shfl_xor(rs[r], d);
    if (col == 0) {
#pragma unroll
        for (int r = 0; r < 4; ++r) ls[wave][q * 4 + r] = rs[r];
    }
    __syncthreads();
    if (tid < 16) {
        float v = ls[0][tid] + ls[1][tid] + ls[2][tid] + ls[3][tid];
        atomicAdd(&sum[pair * 1024 + n0 + tid], v);
    }
}

// ---------------- attention A4: attnS[pair][c][n] = attn[n][c] / sum[n]
__global__ void attnA_scale(const unsigned short* __restrict__ attn_bf,
                            const float* __restrict__ sum, unsigned short* __restrict__ attnS)
{
    int i = blockIdx.x * 256 + threadIdx.x;   // 1,048,576
    int pair = i >> 17;
    int j = i & 131071;
    int c = j >> 10, n = j & 1023;
    int b = pair & 3;
    float rc = 1.f / sum[pair * 1024 + n];
    attnS[(size_t)pair * 131072 + (size_t)c * 1024 + n] =
        f2bf(bf2f(attn_bf[((size_t)(b * 1024 + n)) * 128 + c]) * rc);
}

// ---------------- attention B: recompute S, P=exp(S-mx), LDS transform, PV contract.
// c-split x2: wave = (m-tile, c-half).
__global__ void __launch_bounds__(256)
attn_passB2(const unsigned short* __restrict__ attn_bf,
            const unsigned short* __restrict__ attnS,
            const unsigned short* __restrict__ incT1, const unsigned short* __restrict__ incT2,
            const float* __restrict__ mx,
            const float* __restrict__ inc1f, const float* __restrict__ inc2f,
            float* __restrict__ abuf)
{
    __shared__ unsigned short lp[4][16 * 36];
    int pair = blockIdx.y;
    int b = pair & 3, br = pair >> 2;
    int tid = threadIdx.x;
    int wv = tid >> 6, lane = tid & 63;
    int q = lane >> 4, col = lane & 15;
    int mtile = blockIdx.x * 2 + (wv & 1);
    int chalf = wv >> 1;
    int m0 = mtile * 16;
    const unsigned short* ib = (br ? incT2 : incT1) + (size_t)b * 524288 + (size_t)(m0 + col) * 128 + q * 8;
    short8 bfrS[4];
#pragma unroll
    for (int kc = 0; kc < 4; ++kc) bfrS[kc] = *(const short8*)(ib + kc * 32);
    const float* mxp = mx + pair * 1024;
    const unsigned short* asb = attnS + (size_t)pair * 131072 + (size_t)chalf * 64 * 1024;
    floatx4 oacc[4];
#pragma unroll
    for (int ct = 0; ct < 4; ++ct) oacc[ct] = (floatx4){0.f, 0.f, 0.f, 0.f};
    unsigned short* lw = lp[wv];
    for (int nc = 0; nc < 32; ++nc) {
#pragma unroll
        for (int t = 0; t < 2; ++t) {
            int n0 = nc * 32 + t * 16;
            const unsigned short* ar = attn_bf + ((size_t)(b * 1024 + n0 + col)) * 128 + q * 8;
            floatx4 sacc = (floatx4){0.f, 0.f, 0.f, 0.f};
#pragma unroll
            for (int kc = 0; kc < 4; ++kc)
                sacc = __builtin_amdgcn_mfma_f32_16x16x32_bf16(*(const short8*)(ar + kc * 32), bfrS[kc], sacc, 0, 0, 0);
            floatx4 mxq = *(const floatx4*)(mxp + n0 + q * 4);
            unsigned int p01 = (unsigned int)f2bf(__expf(sacc[0] - mxq[0]))
                             | ((unsigned int)f2bf(__expf(sacc[1] - mxq[1])) << 16);
            unsigned int p23 = (unsigned int)f2bf(__expf(sacc[2] - mxq[2]))
                             | ((unsigned int)f2bf(__expf(sacc[3] - mxq[3])) << 16);
            *(uint2*)&lw[col * 36 + t * 16 + q * 4] = make_uint2(p01, p23);
        }
        short8 pb = *(const short8*)&lw[col * 36 + q * 8];
#pragma unroll
        for (int ct = 0; ct < 4; ++ct) {
            const unsigned short* asr = asb + (size_t)(ct * 16 + col) * 1024 + nc * 32 + q * 8;
            oacc[ct] = __builtin_amdgcn_mfma_f32_16x16x32_bf16(*(const short8*)asr, pb, oacc[ct], 0, 0, 0);
        }
    }
    const float* incp = (br ? inc2f : inc1f) + (size_t)b * 524288;
    float* op = abuf + ((size_t)(b * 256 + br * 128)) * 4096;
    int m = m0 + col;
#pragma unroll
    for (int ct = 0; ct < 4; ++ct)
#pragma unroll
        for (int r = 0; r < 4; ++r) {
            int c = chalf * 64 + ct * 16 + q * 4 + r;
            op[(size_t)c * 4096 + m] = oacc[ct][r] + incp[(size_t)c * 4096 + m];
        }
}

// ---------------- bilinear 2x upsample, half-pixel centers, edge clamp
__global__ void upsample_kernel(const float* __restrict__ in, float* __restrict__ out)
{
    int i = blockIdx.x * 256 + threadIdx.x;
    int x = i & 127, y = (i >> 7) & 127, bc = i >> 14;
    const float* ib = in + (size_t)bc * HW;
    float sy = 0.5f * y - 0.25f;
    float sx = 0.5f * x - 0.25f;
    int y0 = (int)floorf(sy); float ty = sy - y0;
    int x0 = (int)floorf(sx); float tx = sx - x0;
    int y0c = min(max(y0, 0), 63), y1c = min(max(y0 + 1, 0), 63);
    int x0c = min(max(x0, 0), 63), x1c = min(max(x0 + 1, 0), 63);
    float v00 = ib[y0c * 64 + x0c], v01 = ib[y0c * 64 + x1c];
    float v10 = ib[y1c * 64 + x0c], v11 = ib[y1c * 64 + x1c];
    out[i] = (1.f - ty) * ((1.f - tx) * v00 + tx * v01) + ty * ((1.f - tx) * v10 + tx * v11);
}

extern "C" void kernel_launch(void* const* d_in, const int* in_sizes, int n_in,
                              void* d_out, int out_size, void* d_ws, size_t ws_size,
                              hipStream_t stream)
{
    const float* t1       = (const float*)d_in[0];
    const float* t2       = (const float*)d_in[1];
    const float* t1_w     = (const float*)d_in[2];
    const float* t1_b     = (const float*)d_in[3];
    const float* t2_w     = (const float*)d_in[4];
    const float* t2_b     = (const float*)d_in[5];
    const float* df_res_w = (const float*)d_in[6];
    const float* df_res_b = (const float*)d_in[7];
    const float* df_res_s = (const float*)d_in[8];
    const float* df_res_o = (const float*)d_in[9];
    const float* df_b0_w  = (const float*)d_in[10];
    const float* df_b0_b  = (const float*)d_in[11];
    const float* df_b0_s  = (const float*)d_in[12];
    const float* df_b0_o  = (const float*)d_in[13];
    const float* df_b1_w  = (const float*)d_in[14];
    const float* df_b1_b  = (const float*)d_in[15];
    const float* df_b1_s  = (const float*)d_in[16];
    const float* df_b1_o  = (const float*)d_in[17];
    const float* df_fu_w  = (const float*)d_in[18];
    const float* df_fu_b  = (const float*)d_in[19];
    const float* df_fu_s  = (const float*)d_in[20];
    const float* df_fu_o  = (const float*)d_in[21];
    const float* br1_w    = (const float*)d_in[22];
    const float* br1_b    = (const float*)d_in[23];
    const float* br2_w    = (const float*)d_in[24];
    const float* br2_b    = (const float*)d_in[25];
    const float* fu_w     = (const float*)d_in[26];
    const float* fu_b     = (const float*)d_in[27];
    const float* fu_s     = (const float*)d_in[28];
    const float* fu_o     = (const float*)d_in[29];

    float* ws = (float*)d_ws;
    float* res1 = ws;                   // 2,097,152 f  (res1 -> r -> inc1 fp32)
    float* res2 = ws + 2097152;         // 2,097,152 f  (res2 -> b01 -> inc2 fp32)
    float* xbuf = ws + 4194304;         // 4,194,304 f  (x -> dif; fused at +2M)
    float* scr  = ws + 8388608;         // 4,194,304 f  bf16/f32 scratch region
    float* abuf = ws + 12582912;        // 4,194,304 f  concat(a1,a2)
    float* attnS_f = ws + 16777216;     // 524,288 f -> attnS bf16
    float* simv = ws + 17301504;        // 16,384 f
    float* mxb  = ws + 17317888;        // 8,192 f

    unsigned short* us     = (unsigned short*)scr;
    unsigned short* wp_b0  = us;                 // 73,728
    unsigned short* wp_b1  = us + 73728;         // 204,800
    unsigned short* wp_br1 = us + 278528;        // 147,456
    unsigned short* wp_br2 = us + 425984;        // 409,600 -> ends 835,584
    unsigned short* xt_r   = us + 851968;        // 2,367,488 -> ends 3,219,456
    unsigned short* xt_dif = us + 3219456;       // 2,367,488 -> ends 5,586,944
    unsigned short* incT1  = us + 5586944;       // 2,097,152 -> ends 7,684,096
    unsigned short* incT2  = us + 851968;        // 2,097,152 (overlays dead xt_r)
    unsigned short* attn_bf= us + 7684096;       // 524,288 -> ends 8,208,384
    float* sumb            = (float*)(us + 8208384);  // 8,192 f (16,384 u16)
    float* pmaxb           = (float*)(us + 8224768);  // 32,768 f -> ends 8,290,304
    unsigned short* attnS  = (unsigned short*)attnS_f;

    dim3 blk(256);

    // zero padded bf16 conv inputs (xt_r + xt_dif); prepack conv weights
    zero_kernel<<<2312, blk, 0, stream>>>((uint4*)xt_r, 591872);
    prepack_w<<<288,  blk, 0, stream>>>(df_b0_w, wp_b0, 64, 128, 9);
    prepack_w<<<800,  blk, 0, stream>>>(df_b1_w, wp_b1, 64, 128, 25);
    prepack_w<<<576,  blk, 0, stream>>>(br1_w, wp_br1, 128, 128, 9);
    prepack_w<<<1600, blk, 0, stream>>>(br2_w, wp_br2, 128, 128, 25);

    // res1/res2 = 1x1 conv(t1/t2)
    conv1x1_v4<<<dim3(4, 16, 4), blk, 0, stream>>>(t1, t1_w, t1_b, res1, 256, 128, 0, nullptr, nullptr, nullptr, nullptr);
    conv1x1_v4<<<dim3(4, 16, 4), blk, 0, stream>>>(t2, t2_w, t2_b, res2, 256, 128, 0, nullptr, nullptr, nullptr, nullptr);
    sim_kernel<<<4096, blk, 0, stream>>>(res1, res2, simv);
    x_kernel2<<<dim3(128, 4), blk, 0, stream>>>(res1, res2, simv, xbuf);
    simp_kernel2<<<dim3(32, 4), blk, 0, stream>>>(res1, res2, simv, attn_bf);
    // r = stdconv1x1(x) -> res1 (+ bf16 padded copy)
    conv1x1_v4<<<dim3(4, 16, 4), blk, 0, stream>>>(xbuf, df_res_w, df_res_b, res1, 256, 128, 1, df_res_s, df_res_o, nullptr, xt_r);
    // b0 3x3 -> res2[0:64], b1 5x5 -> res2[64:128]
    convk_mfma<3, 64, 1><<<dim3(64, 4), blk, 0, stream>>>(xt_r, wp_b0, df_b0_b, res2, 128, 0, 1, df_b0_s, df_b0_o, nullptr);
    convk_mfma<5, 64, 1><<<dim3(64, 4), blk, 0, stream>>>(xt_r, wp_b1, df_b1_b, res2, 128, 64, 1, df_b1_s, df_b1_o, nullptr);
    // dif = stdconv1x1(b01) + r -> xbuf (+ bf16 padded copy)
    conv1x1_v4<<<dim3(4, 16, 4), blk, 0, stream>>>(res2, df_fu_w, df_fu_b, xbuf, 128, 128, 1, df_fu_s, df_fu_o, res1, xt_dif);
    // inc1/inc2 (fp32 + bf16 transposed incT)
    convk_mfma<3, 128, 2><<<dim3(64, 4), blk, 0, stream>>>(xt_dif, wp_br1, br1_b, res1, 128, 0, 0, nullptr, nullptr, incT1);
    convk_mfma<5, 128, 2><<<dim3(64, 4), blk, 0, stream>>>(xt_dif, wp_br2, br2_b, res2, 128, 0, 0, nullptr, nullptr, incT2);
    // attention
    attnA_max<<<dim3(64, 8, 4), blk, 0, stream>>>(attn_bf, incT1, incT2, pmaxb);
    attnA_merge<<<32, blk, 0, stream>>>(pmaxb, mxb, sumb);
    attnA_sum<<<dim3(64, 8, 4), blk, 0, stream>>>(attn_bf, incT1, incT2, mxb, sumb);
    attnA_scale<<<4096, blk, 0, stream>>>(attn_bf, sumb, attnS);
    attn_passB2<<<dim3(128, 8), blk, 0, stream>>>(attn_bf, attnS, incT1, incT2, mxb, res1, res2, abuf);
    // fused = stdconv1x1(concat(a1,a2)) + dif
    float* dif = xbuf;
    float* fused = xbuf + 2097152;
    conv1x1_v4<<<dim3(4, 16, 4), blk, 0, stream>>>(abuf, fu_w, fu_b, fused, 256, 128, 1, fu_s, fu_o, dif, nullptr);
    // bilinear 2x upsample -> d_out
    upsample_kernel<<<32768, blk, 0, stream>>>(fused, (float*)d_out);
}

// Round 6
// 797.430 us; speedup vs baseline: 1.0936x; 1.0936x over previous
//
#include <hip/hip_runtime.h>
#include <math.h>

#define HW 4096   // 64*64

typedef __attribute__((ext_vector_type(8))) short short8;
typedef __attribute__((ext_vector_type(4))) float floatx4;
typedef __attribute__((ext_vector_type(2))) float floatx2;

__device__ inline unsigned short f2bf(float f) {
    unsigned int u = __float_as_uint(f);
    unsigned int r = (u + 0x7fffu + ((u >> 16) & 1u)) >> 16;
    return (unsigned short)r;
}
__device__ inline float bf2f(unsigned short u) {
    return __uint_as_float(((unsigned int)u) << 16);
}

// ---------------- zero scratch (uint4 stores)
__global__ void zero_kernel(uint4* __restrict__ p, int n)
{
    int i = blockIdx.x * 256 + threadIdx.x;
    if (i < n) p[i] = make_uint4(0u, 0u, 0u, 0u);
}

// ---------------- weight prepack: W[CO][CI][K][K] fp32 -> Wp[kh][kw][co][ci] bf16
__global__ void prepack_w(const float* __restrict__ w, unsigned short* __restrict__ wp,
                          int CO, int CI, int KK)
{
    int i = blockIdx.x * 256 + threadIdx.x;
    if (i >= CO * CI * KK) return;
    int ci = i % CI;
    int t = i / CI;
    int co = t % CO;
    int kk = t / CO;
    wp[i] = f2bf(w[(co * CI + ci) * KK + kk]);
}

// ---------------- 1x1 conv: 2 px/thread (float2), 8 co/thread, weights in LDS
__global__ void __launch_bounds__(256)
conv1x1_v2(const float* __restrict__ in, const float* __restrict__ w,
           const float* __restrict__ bias, float* __restrict__ out,
           int CI, int CO, int do_affine,
           const float* __restrict__ s, const float* __restrict__ o,
           const float* __restrict__ addbuf, unsigned short* __restrict__ xt)
{
    __shared__ float wl[2048];
    int tid = threadIdx.x;
    int c0 = blockIdx.y * 8;
    int b = blockIdx.z;
    for (int i = tid; i < CI * 8; i += 256) {
        int k = i & 7, ci = i >> 3;
        wl[i] = w[(c0 + k) * CI + ci];
    }
    __syncthreads();
    int m = blockIdx.x * 512 + tid * 2;
    floatx2 acc[8];
#pragma unroll
    for (int k = 0; k < 8; ++k) {
        float bv = bias[c0 + k];
        acc[k] = (floatx2){bv, bv};
    }
    const float* inb = in + (size_t)b * CI * HW + m;
#pragma unroll 4
    for (int ci = 0; ci < CI; ++ci) {
        floatx2 v = *(const floatx2*)(inb + (size_t)ci * HW);
#pragma unroll
        for (int k = 0; k < 8; ++k) acc[k] += wl[ci * 8 + k] * v;
    }
#pragma unroll
    for (int k = 0; k < 8; ++k) {
        floatx2 v = acc[k];
        if (do_affine) {
            float sc = s[c0 + k], of = o[c0 + k];
            v[0] = fmaxf(v[0], 0.f) * sc + of;
            v[1] = fmaxf(v[1], 0.f) * sc + of;
        }
        size_t oidx = ((size_t)(b * CO + c0 + k)) * HW + m;
        if (addbuf) v += *(const floatx2*)(addbuf + oidx);
        *(floatx2*)(out + oidx) = v;
        acc[k] = v;
    }
    if (xt) {
#pragma unroll
        for (int r = 0; r < 2; ++r) {
            int mm = m + r;
            union { unsigned short u16[8]; uint4 q; } pk;
#pragma unroll
            for (int k = 0; k < 8; ++k) pk.u16[k] = f2bf(acc[k][r]);
            int h = mm >> 6, wc = mm & 63;
            *(uint4*)(xt + ((size_t)b * 4624 + (h + 2) * 68 + (wc + 2)) * 128 + c0) = pk.q;
        }
    }
}

// ---------------- KxK conv as implicit-GEMM bf16 MFMA, m-split MS for occupancy
template<int K, int CO, int NB, int MS>
__global__ void __launch_bounds__(256)
convk_mfma(const unsigned short* __restrict__ xt, const unsigned short* __restrict__ wp,
           const float* __restrict__ bias, float* __restrict__ out,
           int OB, int co_off, int do_affine,
           const float* __restrict__ s, const float* __restrict__ o,
           unsigned short* __restrict__ incT)
{
    constexpr int CI = 128;
    constexpr int PAD = K / 2;
    constexpr int RO = 2 - PAD;
    constexpr int MT = 4 / MS;
    int tid = threadIdx.x;
    int wave = tid >> 6, lane = tid & 63;
    int h = blockIdx.x / MS, msb = blockIdx.x % MS;
    int b = blockIdx.y;
    int co0 = wave * 16 * NB;
    int n = lane & 15, q = lane >> 4;
    floatx4 acc[MT][NB];
#pragma unroll
    for (int mt = 0; mt < MT; ++mt)
#pragma unroll
        for (int nt = 0; nt < NB; ++nt) acc[mt][nt] = (floatx4){0.f, 0.f, 0.f, 0.f};

    const unsigned short* xb = xt + (size_t)b * (68 * 68 * 128) + 8 * q;
    int mbase = msb * MT * 16;
    for (int ci0 = 0; ci0 < CI; ci0 += 32) {
#pragma unroll
        for (int kh = 0; kh < K; ++kh) {
            const unsigned short* xrow = xb + (size_t)(((h + kh + RO) * 68 + RO) * 128 + ci0);
            const unsigned short* wrow = wp + (size_t)(kh * K * CO * CI) + ci0 + 8 * q;
#pragma unroll
            for (int kw = 0; kw < K; ++kw) {
                short8 bfr[NB];
#pragma unroll
                for (int nt = 0; nt < NB; ++nt)
                    bfr[nt] = *(const short8*)(wrow + (size_t)((kw * CO + co0 + nt * 16 + n) * CI));
#pragma unroll
                for (int mt = 0; mt < MT; ++mt) {
                    short8 afr = *(const short8*)(xrow + (mbase + mt * 16 + n + kw) * 128);
#pragma unroll
                    for (int nt = 0; nt < NB; ++nt)
                        acc[mt][nt] = __builtin_amdgcn_mfma_f32_16x16x32_bf16(afr, bfr[nt], acc[mt][nt], 0, 0, 0);
                }
            }
        }
    }
    int px0 = h * 64 + mbase + q * 4;
#pragma unroll
    for (int nt = 0; nt < NB; ++nt) {
        int co = co0 + nt * 16 + n;
        float bi = bias[co];
        float sc = do_affine ? s[co] : 1.f;
        float of = do_affine ? o[co] : 0.f;
        float* ob = out + ((size_t)(b * OB + co_off + co)) * HW;
        unsigned short* tb = incT ? incT + (size_t)b * (4096 * 128) + co : nullptr;
#pragma unroll
        for (int mt = 0; mt < MT; ++mt)
#pragma unroll
            for (int r = 0; r < 4; ++r) {
                int px = px0 + mt * 16 + r;
                float v = acc[mt][nt][r] + bi;
                if (do_affine) v = fmaxf(v, 0.f) * sc + of;
                ob[px] = v;
                if (incT) tb[(size_t)px * 128] = f2bf(v);
            }
    }
}

// ---------------- cosine similarity over groups of 128 consecutive floats
__global__ void sim_kernel(const float* __restrict__ r1, const float* __restrict__ r2,
                           float* __restrict__ sim)
{
    int gw = blockIdx.x * 4 + (threadIdx.x >> 6);
    int lane = threadIdx.x & 63;
    int b = gw >> 12, n = gw & 4095;
    const float* p1 = r1 + (size_t)b * 524288 + (size_t)n * 128;
    const float* p2 = r2 + (size_t)b * 524288 + (size_t)n * 128;
    float a0 = p1[lane], a1 = p1[lane + 64];
    float b0 = p2[lane], b1 = p2[lane + 64];
    float dot = a0 * b0 + a1 * b1;
    float n1 = a0 * a0 + a1 * a1;
    float n2 = b0 * b0 + b1 * b1;
    for (int m = 32; m; m >>= 1) {
        dot += __shfl_xor(dot, m);
        n1  += __shfl_xor(n1, m);
        n2  += __shfl_xor(n2, m);
    }
    if (lane == 0) sim[b * 4096 + n] = dot / fmaxf(sqrtf(n1) * sqrtf(n2), 1e-8f);
}

// ---------------- x = concat(dif1, dif2): LDS-transposed, coalesced
__global__ void __launch_bounds__(256)
x_kernel2(const float* __restrict__ r1, const float* __restrict__ r2,
          const float* __restrict__ sim, float* __restrict__ xo)
{
    __shared__ float ls1[32 * 129], ls2[32 * 129];
    int b = blockIdx.y, p0 = blockIdx.x * 32, tid = threadIdx.x;
    const float* F1 = r1 + (size_t)b * 524288;
    const float* F2 = r2 + (size_t)b * 524288;
    for (int i = tid; i < 32 * 128; i += 256) {
        int p = i >> 7, c = i & 127;
        ls1[p * 129 + c] = F1[p0 * 128 + i];
        ls2[p * 129 + c] = F2[p0 * 128 + i];
    }
    __syncthreads();
    for (int j = tid; j < 256 * 32; j += 256) {
        int p = j & 31, cc = j >> 5;
        int c = cc & 127;
        float sv = sim[b * 4096 + p0 + p];
        const float* F = (cc & 128) ? F2 : F1;
        float t1v = ((cc & 128) ? ls2 : ls1)[p * 129 + c];
        xo[(size_t)b * 1048576 + (size_t)cc * 4096 + p0 + p] = t1v * (1.f - sv) + F[(size_t)c * 4096 + p0 + p];
    }
}

// ---------------- attn = avgpool2(|sim1-sim2|) -> bf16 [b][c][n], channel-split
__global__ void __launch_bounds__(256)
simp_kernel3(const float* __restrict__ r1, const float* __restrict__ r2,
             const float* __restrict__ sim, unsigned short* __restrict__ attn_bf)
{
    __shared__ float lsd[64 * 33];
    int b = blockIdx.y, h2 = blockIdx.x, cg = blockIdx.z, tid = threadIdx.x;
    const float* F1 = r1 + (size_t)b * 524288;
    const float* F2 = r2 + (size_t)b * 524288;
    const float* sb = sim + b * 4096;
    int w2 = tid & 31, cl = tid >> 5;
    float acc[4] = {};
    for (int dh = 0; dh < 2; ++dh) {
        int prow = h2 * 128 + dh * 64;
        __syncthreads();
        for (int i = tid; i < 64 * 32; i += 256) {
            int p = i >> 5, c = i & 31;
            size_t gi = (size_t)(prow + p) * 128 + cg * 32 + c;
            lsd[p * 33 + c] = F1[gi] - F2[gi];
        }
        __syncthreads();
#pragma unroll
        for (int k = 0; k < 4; ++k) {
            int c = cl + 8 * k;
            int cG = cg * 32 + c;
#pragma unroll
            for (int dw = 0; dw < 2; ++dw) {
                int pl = 2 * w2 + dw;
                int p = prow + pl;
                float d = lsd[pl * 33 + c] * sb[p]
                        + (F1[(size_t)cG * 4096 + p] - F2[(size_t)cG * 4096 + p]);
                acc[k] += fabsf(d);
            }
        }
    }
#pragma unroll
    for (int k = 0; k < 4; ++k) {
        int cG = cg * 32 + cl + 8 * k;
        attn_bf[(size_t)b * 131072 + (size_t)cG * 1024 + h2 * 32 + w2] = f2bf(acc[k] * 0.25f);
    }
}

// ---------------- attention pass1: fused online (max,sum) partials, z-split
__global__ void __launch_bounds__(256)
attnA_pass1(const unsigned short* __restrict__ attn_bf,
            const unsigned short* __restrict__ incT1, const unsigned short* __restrict__ incT2,
            float* __restrict__ pmax, float* __restrict__ psum)
{
    __shared__ float lm[4][16], ls[4][16];
    int pair = blockIdx.y;
    int b = pair & 3, br = pair >> 2;
    int z = blockIdx.z;
    int tid = threadIdx.x;
    int wave = tid >> 6, lane = tid & 63;
    int n0 = blockIdx.x * 16;
    int q = lane >> 4, col = lane & 15;
    const unsigned short* arow = attn_bf + ((size_t)(b * 1024 + n0 + col)) * 128 + q * 8;
    short8 afr[4];
#pragma unroll
    for (int kc = 0; kc < 4; ++kc) afr[kc] = *(const short8*)(arow + kc * 32);
    const unsigned short* ib = (br ? incT2 : incT1) + (size_t)b * 524288;
    float rm[4], rs[4];
#pragma unroll
    for (int r = 0; r < 4; ++r) { rm[r] = -3.0e38f; rs[r] = 0.f; }
#pragma unroll 2
    for (int mt = 0; mt < 16; ++mt) {
        int m = z * 1024 + wave * 256 + mt * 16 + col;
        const unsigned short* brow = ib + (size_t)m * 128 + q * 8;
        floatx4 acc = (floatx4){0.f, 0.f, 0.f, 0.f};
#pragma unroll
        for (int kc = 0; kc < 4; ++kc)
            acc = __builtin_amdgcn_mfma_f32_16x16x32_bf16(afr[kc], *(const short8*)(brow + kc * 32), acc, 0, 0, 0);
#pragma unroll
        for (int r = 0; r < 4; ++r) {
            float v = acc[r];
            float nm = fmaxf(rm[r], v);
            rs[r] = rs[r] * __expf(rm[r] - nm) + __expf(v - nm);
            rm[r] = nm;
        }
    }
#pragma unroll
    for (int d = 1; d < 16; d <<= 1) {
#pragma unroll
        for (int r = 0; r < 4; ++r) {
            float om = __shfl_xor(rm[r], d);
            float os = __shfl_xor(rs[r], d);
            float nm = fmaxf(rm[r], om);
            rs[r] = rs[r] * __expf(rm[r] - nm) + os * __expf(om - nm);
            rm[r] = nm;
        }
    }
    if (col == 0) {
#pragma unroll
        for (int r = 0; r < 4; ++r) { lm[wave][q * 4 + r] = rm[r]; ls[wave][q * 4 + r] = rs[r]; }
    }
    __syncthreads();
    if (tid < 16) {
        float bm = lm[0][tid], bs = ls[0][tid];
        for (int w = 1; w < 4; ++w) {
            float om = lm[w][tid], os = ls[w][tid];
            float nm = fmaxf(bm, om);
            bs = bs * __expf(bm - nm) + os * __expf(om - nm);
            bm = nm;
        }
        pmax[((size_t)pair * 4 + z) * 1024 + n0 + tid] = bm;
        psum[((size_t)pair * 4 + z) * 1024 + n0 + tid] = bs;
    }
}

// ---------------- attention merge: combine z partials -> mx, 1/sum
__global__ void attnA_merge2(const float* __restrict__ pmax, const float* __restrict__ psum,
                             float* __restrict__ mx, float* __restrict__ rsb)
{
    int i = blockIdx.x * 256 + threadIdx.x;   // 8192
    int pair = i >> 10, n = i & 1023;
    float bm = pmax[((size_t)pair * 4) * 1024 + n];
    float bs = psum[((size_t)pair * 4) * 1024 + n];
    for (int z = 1; z < 4; ++z) {
        float om = pmax[((size_t)pair * 4 + z) * 1024 + n];
        float os = psum[((size_t)pair * 4 + z) * 1024 + n];
        float nm = fmaxf(bm, om);
        bs = bs * __expf(bm - nm) + os * __expf(om - nm);
        bm = nm;
    }
    mx[i] = bm;
    rsb[i] = 1.f / bs;
}

// ---------------- attnS[pair][c][n] = attn[n][c] * rsb[n]
__global__ void attnA_scale(const unsigned short* __restrict__ attn_bf,
                            const float* __restrict__ rsb, unsigned short* __restrict__ attnS)
{
    int i = blockIdx.x * 256 + threadIdx.x;   // 1,048,576
    int pair = i >> 17;
    int j = i & 131071;
    int c = j >> 10, n = j & 1023;
    int b = pair & 3;
    float rc = rsb[pair * 1024 + n];
    attnS[(size_t)pair * 131072 + (size_t)c * 1024 + n] =
        f2bf(bf2f(attn_bf[((size_t)(b * 1024 + n)) * 128 + c]) * rc);
}

// ---------------- abuf init = residual copy (inc1 -> [0:128], inc2 -> [128:256])
__global__ void abuf_init(const float* __restrict__ inc1, const float* __restrict__ inc2,
                          float* __restrict__ abuf)
{
    int pair = blockIdx.y;
    int b = pair & 3, br = pair >> 2;
    int i = blockIdx.x * 256 + threadIdx.x;   // 131072 float4 per (b,br)
    const float4* src = (const float4*)((br ? inc2 : inc1) + (size_t)b * 524288);
    float4* dst = (float4*)(abuf + ((size_t)(b * 256 + br * 128)) * 4096);
    dst[i] = src[i];
}

// ---------------- attention pass B: n-split x2, prefetched, atomicAdd partials
__global__ void __launch_bounds__(256)
attn_passB3(const unsigned short* __restrict__ attn_bf,
            const unsigned short* __restrict__ attnS,
            const unsigned short* __restrict__ incT1, const unsigned short* __restrict__ incT2,
            const float* __restrict__ mx, float* __restrict__ abuf)
{
    __shared__ unsigned short lp[4][16 * 36];
    int pair = blockIdx.y;
    int b = pair & 3, br = pair >> 2;
    int tid = threadIdx.x;
    int wv = tid >> 6, lane = tid & 63;
    int q = lane >> 4, col = lane & 15;
    int msub = wv & 1, nh = wv >> 1;
    int m0 = blockIdx.x * 32 + msub * 16;
    const unsigned short* ib = (br ? incT2 : incT1) + (size_t)b * 524288 + (size_t)(m0 + col) * 128 + q * 8;
    short8 bfrS[4];
#pragma unroll
    for (int kc = 0; kc < 4; ++kc) bfrS[kc] = *(const short8*)(ib + kc * 32);
    const float* mxp = mx + pair * 1024 + nh * 512;
    const unsigned short* asb = attnS + (size_t)pair * 131072 + nh * 512;
    const unsigned short* abase = attn_bf + ((size_t)(b * 1024 + nh * 512 + col)) * 128 + q * 8;
    floatx4 oacc[8];
#pragma unroll
    for (int ct = 0; ct < 8; ++ct) oacc[ct] = (floatx4){0.f, 0.f, 0.f, 0.f};
    unsigned short* lw = lp[wv];
    short8 arP[2][4];
#pragma unroll
    for (int t = 0; t < 2; ++t)
#pragma unroll
        for (int kc = 0; kc < 4; ++kc)
            arP[t][kc] = *(const short8*)(abase + (size_t)(t * 16) * 128 + kc * 32);
    for (int nc = 0; nc < 16; ++nc) {
        floatx4 sacc[2];
#pragma unroll
        for (int t = 0; t < 2; ++t) {
            sacc[t] = (floatx4){0.f, 0.f, 0.f, 0.f};
#pragma unroll
            for (int kc = 0; kc < 4; ++kc)
                sacc[t] = __builtin_amdgcn_mfma_f32_16x16x32_bf16(arP[t][kc], bfrS[kc], sacc[t], 0, 0, 0);
        }
        // prefetch next iteration's attn tiles (overlaps exp/LDS/PV below)
        if (nc < 15) {
#pragma unroll
            for (int t = 0; t < 2; ++t)
#pragma unroll
                for (int kc = 0; kc < 4; ++kc)
                    arP[t][kc] = *(const short8*)(abase + (size_t)((nc + 1) * 32 + t * 16) * 128 + kc * 32);
        }
#pragma unroll
        for (int t = 0; t < 2; ++t) {
            floatx4 mxq = *(const floatx4*)(mxp + nc * 32 + t * 16 + q * 4);
            unsigned int p01 = (unsigned int)f2bf(__expf(sacc[t][0] - mxq[0]))
                             | ((unsigned int)f2bf(__expf(sacc[t][1] - mxq[1])) << 16);
            unsigned int p23 = (unsigned int)f2bf(__expf(sacc[t][2] - mxq[2]))
                             | ((unsigned int)f2bf(__expf(sacc[t][3] - mxq[3])) << 16);
            *(uint2*)&lw[col * 36 + t * 16 + q * 4] = make_uint2(p01, p23);
        }
        short8 pb = *(const short8*)&lw[col * 36 + q * 8];
#pragma unroll
        for (int ct = 0; ct < 8; ++ct) {
            const unsigned short* asr = asb + (size_t)(ct * 16 + col) * 1024 + nc * 32 + q * 8;
            oacc[ct] = __builtin_amdgcn_mfma_f32_16x16x32_bf16(*(const short8*)asr, pb, oacc[ct], 0, 0, 0);
        }
    }
    float* op = abuf + ((size_t)(b * 256 + br * 128)) * 4096;
    int m = m0 + col;
#pragma unroll
    for (int ct = 0; ct < 8; ++ct)
#pragma unroll
        for (int r = 0; r < 4; ++r)
            atomicAdd(&op[(size_t)(ct * 16 + q * 4 + r) * 4096 + m], oacc[ct][r]);
}

// ---------------- bilinear 2x upsample, half-pixel centers, edge clamp
__global__ void upsample_kernel(const float* __restrict__ in, float* __restrict__ out)
{
    int i = blockIdx.x * 256 + threadIdx.x;
    int x = i & 127, y = (i >> 7) & 127, bc = i >> 14;
    const float* ib = in + (size_t)bc * HW;
    float sy = 0.5f * y - 0.25f;
    float sx = 0.5f * x - 0.25f;
    int y0 = (int)floorf(sy); float ty = sy - y0;
    int x0 = (int)floorf(sx); float tx = sx - x0;
    int y0c = min(max(y0, 0), 63), y1c = min(max(y0 + 1, 0), 63);
    int x0c = min(max(x0, 0), 63), x1c = min(max(x0 + 1, 0), 63);
    float v00 = ib[y0c * 64 + x0c], v01 = ib[y0c * 64 + x1c];
    float v10 = ib[y1c * 64 + x0c], v11 = ib[y1c * 64 + x1c];
    out[i] = (1.f - ty) * ((1.f - tx) * v00 + tx * v01) + ty * ((1.f - tx) * v10 + tx * v11);
}

extern "C" void kernel_launch(void* const* d_in, const int* in_sizes, int n_in,
                              void* d_out, int out_size, void* d_ws, size_t ws_size,
                              hipStream_t stream)
{
    const float* t1       = (const float*)d_in[0];
    const float* t2       = (const float*)d_in[1];
    const float* t1_w     = (const float*)d_in[2];
    const float* t1_b     = (const float*)d_in[3];
    const float* t2_w     = (const float*)d_in[4];
    const float* t2_b     = (const float*)d_in[5];
    const float* df_res_w = (const float*)d_in[6];
    const float* df_res_b = (const float*)d_in[7];
    const float* df_res_s = (const float*)d_in[8];
    const float* df_res_o = (const float*)d_in[9];
    const float* df_b0_w  = (const float*)d_in[10];
    const float* df_b0_b  = (const float*)d_in[11];
    const float* df_b0_s  = (const float*)d_in[12];
    const float* df_b0_o  = (const float*)d_in[13];
    const float* df_b1_w  = (const float*)d_in[14];
    const float* df_b1_b  = (const float*)d_in[15];
    const float* df_b1_s  = (const float*)d_in[16];
    const float* df_b1_o  = (const float*)d_in[17];
    const float* df_fu_w  = (const float*)d_in[18];
    const float* df_fu_b  = (const float*)d_in[19];
    const float* df_fu_s  = (const float*)d_in[20];
    const float* df_fu_o  = (const float*)d_in[21];
    const float* br1_w    = (const float*)d_in[22];
    const float* br1_b    = (const float*)d_in[23];
    const float* br2_w    = (const float*)d_in[24];
    const float* br2_b    = (const float*)d_in[25];
    const float* fu_w     = (const float*)d_in[26];
    const float* fu_b     = (const float*)d_in[27];
    const float* fu_s     = (const float*)d_in[28];
    const float* fu_o     = (const float*)d_in[29];

    float* ws = (float*)d_ws;
    float* res1 = ws;                   // 2,097,152 f  (res1 -> r -> inc1 fp32)
    float* res2 = ws + 2097152;         // 2,097,152 f  (res2 -> b01 -> inc2 fp32)
    float* xbuf = ws + 4194304;         // 4,194,304 f  (x -> dif; fused at +2M)
    float* scr  = ws + 8388608;         // 4,194,304 f  bf16/f32 scratch region
    float* abuf = ws + 12582912;        // 4,194,304 f  concat(a1,a2)
    float* attnS_f = ws + 16777216;     // 524,288 f -> attnS bf16
    float* simv = ws + 17301504;        // 16,384 f
    float* mxb  = ws + 17317888;        // 8,192 f

    unsigned short* us     = (unsigned short*)scr;
    unsigned short* wp_b0  = us;                 // 73,728
    unsigned short* wp_b1  = us + 73728;         // 204,800
    unsigned short* wp_br1 = us + 278528;        // 147,456
    unsigned short* wp_br2 = us + 425984;        // 409,600 -> ends 835,584
    unsigned short* xt_r   = us + 851968;        // 2,367,488 -> ends 3,219,456
    unsigned short* xt_dif = us + 3219456;       // 2,367,488 -> ends 5,586,944
    unsigned short* incT1  = us + 5586944;       // 2,097,152 -> ends 7,684,096
    unsigned short* incT2  = us + 851968;        // 2,097,152 (overlays dead xt_r)
    unsigned short* attn_bf= us + 7684096;       // 524,288 -> ends 8,208,384 (f 4,104,192)
    float* scrF = scr;
    float* pmaxb = scrF + 4104192;      // 32,768 f
    float* psumb = scrF + 4136960;      // 32,768 f
    float* rsb   = scrF + 4169728;      // 8,192 f -> ends 4,177,920 < 4,194,304
    unsigned short* attnS  = (unsigned short*)attnS_f;

    dim3 blk(256);

    // zero padded bf16 conv inputs (xt_r + xt_dif); prepack conv weights
    zero_kernel<<<2312, blk, 0, stream>>>((uint4*)xt_r, 591872);
    prepack_w<<<288,  blk, 0, stream>>>(df_b0_w, wp_b0, 64, 128, 9);
    prepack_w<<<800,  blk, 0, stream>>>(df_b1_w, wp_b1, 64, 128, 25);
    prepack_w<<<576,  blk, 0, stream>>>(br1_w, wp_br1, 128, 128, 9);
    prepack_w<<<1600, blk, 0, stream>>>(br2_w, wp_br2, 128, 128, 25);

    // res1/res2 = 1x1 conv(t1/t2)
    conv1x1_v2<<<dim3(8, 16, 4), blk, 0, stream>>>(t1, t1_w, t1_b, res1, 256, 128, 0, nullptr, nullptr, nullptr, nullptr);
    conv1x1_v2<<<dim3(8, 16, 4), blk, 0, stream>>>(t2, t2_w, t2_b, res2, 256, 128, 0, nullptr, nullptr, nullptr, nullptr);
    sim_kernel<<<4096, blk, 0, stream>>>(res1, res2, simv);
    x_kernel2<<<dim3(128, 4), blk, 0, stream>>>(res1, res2, simv, xbuf);
    simp_kernel3<<<dim3(32, 4, 4), blk, 0, stream>>>(res1, res2, simv, attn_bf);
    // r = stdconv1x1(x) -> res1 (+ bf16 padded copy)
    conv1x1_v2<<<dim3(8, 16, 4), blk, 0, stream>>>(xbuf, df_res_w, df_res_b, res1, 256, 128, 1, df_res_s, df_res_o, nullptr, xt_r);
    // b0 3x3 -> res2[0:64], b1 5x5 -> res2[64:128]
    convk_mfma<3, 64, 1, 2><<<dim3(128, 4), blk, 0, stream>>>(xt_r, wp_b0, df_b0_b, res2, 128, 0, 1, df_b0_s, df_b0_o, nullptr);
    convk_mfma<5, 64, 1, 2><<<dim3(128, 4), blk, 0, stream>>>(xt_r, wp_b1, df_b1_b, res2, 128, 64, 1, df_b1_s, df_b1_o, nullptr);
    // dif = stdconv1x1(b01) + r -> xbuf (+ bf16 padded copy)
    conv1x1_v2<<<dim3(8, 16, 4), blk, 0, stream>>>(res2, df_fu_w, df_fu_b, xbuf, 128, 128, 1, df_fu_s, df_fu_o, res1, xt_dif);
    // inc1/inc2 (fp32 + bf16 transposed incT)
    convk_mfma<3, 128, 2, 2><<<dim3(128, 4), blk, 0, stream>>>(xt_dif, wp_br1, br1_b, res1, 128, 0, 0, nullptr, nullptr, incT1);
    convk_mfma<5, 128, 2, 2><<<dim3(128, 4), blk, 0, stream>>>(xt_dif, wp_br2, br2_b, res2, 128, 0, 0, nullptr, nullptr, incT2);
    // attention
    attnA_pass1<<<dim3(64, 8, 4), blk, 0, stream>>>(attn_bf, incT1, incT2, pmaxb, psumb);
    attnA_merge2<<<32, blk, 0, stream>>>(pmaxb, psumb, mxb, rsb);
    attnA_scale<<<4096, blk, 0, stream>>>(attn_bf, rsb, attnS);
    abuf_init<<<dim3(512, 8), blk, 0, stream>>>(res1, res2, abuf);
    attn_passB3<<<dim3(128, 8), blk, 0, stream>>>(attn_bf, attnS, incT1, incT2, mxb, abuf);
    // fused = stdconv1x1(concat(a1,a2)) + dif
    float* dif = xbuf;
    float* fused = xbuf + 2097152;
    conv1x1_v2<<<dim3(8, 16, 4), blk, 0, stream>>>(abuf, fu_w, fu_b, fused, 256, 128, 1, fu_s, fu_o, dif, nullptr);
    // bilinear 2x upsample -> d_out
    upsample_kernel<<<32768, blk, 0, stream>>>(fused, (float*)d_out);
}